// Round 11
// baseline (661.804 us; speedup 1.0000x reference)
//
#include <hip/hip_runtime.h>
#include <hip/hip_fp16.h>
#include <hip/hip_cooperative_groups.h>

// GraphEncoder: 3x GraphConv(norm='both'), DIM=64, fixed graph.
// R11: R10 mega-kernel fixed.
//  - Root cause of R10 fail: Ws4[3] = 48KB LDS -> 3 blocks/CU -> 1024-block
//    cooperative launch rejected (return code ignored) -> no-op, zero output.
//  - Fix: stage ONE layer's W (16KB), reload after each grid.sync. LDS ~18KB,
//    launch_bounds(256,4) -> 4 blocks/CU -> 1024 blocks co-resident = legal.
//  - Cooperative launch return code checked; fallback = perm+prescale+3 layer
//    kernels (identical math) if rejected.
// Degree-sorted wave packing (LPT) + fp16 tables + fp32 math as before.

namespace cg = cooperative_groups;

#define N_NODES 65536
#define N_EDGES 1048576
#define DIM 64

#define CHUNKS 256
#define EPC (N_EDGES / CHUNKS)        // 4096 edges per scatter chunk
#define HB 128                        // edge_hist blocks (2 chunks each)
#define OH_WORDS 16384                // 65536 nodes packed 4-per-word (64KB)
#define MB 1024                       // mega-kernel blocks (4/CU co-resident)

struct alignas(8) h4 { __half2 a, b; };   // 4 halves = 8 B

// --- one pass over edges: dst partition hist + packed src hist + zero rows ---
__global__ void edge_hist(const int* __restrict__ src, const int* __restrict__ dst,
                          int* __restrict__ block_hist, unsigned* __restrict__ partial,
                          uint2* __restrict__ zeroA, uint2* __restrict__ zeroB) {
    __shared__ unsigned h[OH_WORDS];  // 64 KB: src histogram, 8-bit x4 packed
    __shared__ int bh[2][256];
    int t = threadIdx.x;
    int j = blockIdx.x;               // 0..127
    for (int i = t; i < OH_WORDS; i += 256) h[i] = 0;
    bh[0][t] = 0; bh[1][t] = 0;
    __syncthreads();
    if (j == 0) {                     // zero row (row N_NODES, 128 B each table)
        if (t < 16) zeroA[t] = make_uint2(0u, 0u);
        else if (t < 32) zeroB[t - 16] = make_uint2(0u, 0u);
    }
    int base = j * (2 * EPC);
    for (int i = t; i < 2 * EPC; i += 256) {
        int s = src[base + i];
        int d = dst[base + i];
        atomicAdd(&h[s >> 2], 1u << ((s & 3) * 8));
        atomicAdd(&bh[i >> 12][d >> 8], 1);
    }
    __syncthreads();
    unsigned* dp = partial + (size_t)j * OH_WORDS;
    for (int i = t; i < OH_WORDS; i += 256) dp[i] = h[i];
    block_hist[t * CHUNKS + 2 * j]     = bh[0][t];
    block_hist[t * CHUNKS + 2 * j + 1] = bh[1][t];
}

// --- exclusive scan of 65536 (bucket-major [bucket][chunk]) ---
__global__ void part_scan(const int* __restrict__ bh, int* __restrict__ so) {
    __shared__ int s[1024];
    int t = threadIdx.x;
    const int4* b4 = (const int4*)(bh + t * 64);
    int4 v[16];
    int sum = 0;
    #pragma unroll
    for (int i = 0; i < 16; i++) {
        v[i] = b4[i];
        sum += v[i].x + v[i].y + v[i].z + v[i].w;
    }
    s[t] = sum;
    __syncthreads();
    for (int off = 1; off < 1024; off <<= 1) {
        int u = (t >= off) ? s[t - off] : 0;
        __syncthreads();
        s[t] += u;
        __syncthreads();
    }
    int run = s[t] - sum;
    int* o = so + t * 64;
    #pragma unroll
    for (int i = 0; i < 16; i++) {
        o[4 * i + 0] = run; run += v[i].x;
        o[4 * i + 1] = run; run += v[i].y;
        o[4 * i + 2] = run; run += v[i].z;
        o[4 * i + 3] = run; run += v[i].w;
    }
}

// --- scatter packed (src | dlow<<16) into bucket order, 256 chunks ---
__global__ void part_scatter(const int* __restrict__ src, const int* __restrict__ dst,
                             const int* __restrict__ so, int* __restrict__ bpack) {
    __shared__ int cur[256];
    cur[threadIdx.x] = so[threadIdx.x * CHUNKS + blockIdx.x];
    __syncthreads();
    int base = blockIdx.x * EPC;
    for (int i = threadIdx.x; i < EPC; i += 256) {
        int s = src[base + i];
        int d = dst[base + i];
        int pos = atomicAdd(&cur[d >> 8], 1);
        bpack[pos] = s | ((d & 255) << 16);
    }
}

// --- per-bucket: hist -> scan -> row_start+rs_in+class key/counts -> csr emit ---
__global__ void bucket_fused(const int* __restrict__ bpack, const int* __restrict__ so,
                             int* __restrict__ row_start, float* __restrict__ rs_in,
                             unsigned short* __restrict__ csr_src,
                             unsigned char* __restrict__ key, int* __restrict__ cnt) {
    __shared__ int stage[8192];                        // 32 KB
    __shared__ int h[256], sc[256], cur[256];
    __shared__ int cnt16[16];
    int b = blockIdx.x;
    int t = threadIdx.x;
    int beg = so[b * CHUNKS];
    int end = (b == 255) ? N_EDGES : so[(b + 1) * CHUNKS];
    int n = end - beg;
    h[t] = 0;
    if (t < 16) cnt16[t] = 0;
    __syncthreads();
    for (int i = t; i < n; i += 256) {
        int p = bpack[beg + i];
        if (i < 8192) stage[i] = p;
        atomicAdd(&h[(p >> 16) & 255], 1);
    }
    __syncthreads();
    int d = h[t];
    sc[t] = d;
    __syncthreads();
    for (int off = 1; off < 256; off <<= 1) {
        int v = (t >= off) ? sc[t - off] : 0;
        __syncthreads();
        sc[t] += v;
        __syncthreads();
    }
    int rsv = beg + sc[t] - d;
    int node = b * 256 + t;
    row_start[node] = rsv;
    rs_in[node] = rsqrtf(d < 1 ? 1.0f : (float)d);
    if (node == N_NODES - 1) row_start[N_NODES] = N_EDGES;
    // degree class (descending trip count = LPT): k = 15 - min(15, ceil(d/16))
    int c = (d + 15) >> 4; if (c > 15) c = 15;
    int k = 15 - c;
    key[node] = (unsigned char)k;
    atomicAdd(&cnt16[k], 1);
    cur[t] = rsv;
    __syncthreads();
    if (t < 16) cnt[b * 16 + t] = cnt16[t];
    for (int i = t; i < n; i += 256) {
        int p = (i < 8192) ? stage[i] : bpack[beg + i];
        int pos = atomicAdd(&cur[(p >> 16) & 255], 1);
        csr_src[pos] = (unsigned short)(p & 0xFFFF);
    }
}

// ================= shared device helpers (mega + fallback) =================

__device__ __forceinline__ void perm_slice(const int* cnt, const unsigned char* key,
                                           int* perm, int j, int t,
                                           int* tots, int* basel, int* binb, int* cur16) {
    if (t < 16) {
        int run = 0, bj = 0;
        for (int j2 = 0; j2 < 256; j2++) {
            if (j2 == j) bj = run;
            run += cnt[j2 * 16 + t];
        }
        tots[t] = run;
        basel[t] = bj;
    }
    __syncthreads();
    if (t == 0) {
        int r = 0;
        for (int i = 0; i < 16; i++) { binb[i] = r; r += tots[i]; }
    }
    __syncthreads();
    if (t < 16) cur16[t] = binb[t] + basel[t];
    __syncthreads();
    int node = j * 256 + t;
    int k = key[node];
    int pos = atomicAdd(&cur16[k], 1);
    perm[pos] = node;
}

template<bool SCALE_OUT>
__device__ __forceinline__ void layer_tile(const h4* __restrict__ xs,
                                           const int* __restrict__ row_start,
                                           const unsigned short* __restrict__ csr,
                                           const float* __restrict__ rs_out,
                                           const float* __restrict__ rs_in,
                                           const float4* Ws4, const float4* bs4,
                                           void* outp, int node, int g, int l) {
    int beg = row_start[node];
    int end = row_start[node + 1];
    float4 acc = make_float4(0.f, 0.f, 0.f, 0.f);
    for (int k = beg; k < end; k += 16) {
        int s[16];
        #pragma unroll
        for (int jj = 0; jj < 16; jj++) {
            int kk = k + jj;
            int idx = csr[kk];                         // csr padded by 16 -> safe
            s[jj] = (kk < end) ? idx : N_NODES;        // OOB -> zero row (L1-hot)
        }
        h4 v[16];
        #pragma unroll
        for (int jj = 0; jj < 16; jj++) v[jj] = xs[s[jj] * 16 + l];
        #pragma unroll
        for (int jj = 0; jj < 16; jj++) {
            float2 lo = __half22float2(v[jj].a);
            float2 hi = __half22float2(v[jj].b);
            acc.x += lo.x; acc.y += lo.y; acc.z += hi.x; acc.w += hi.y;
        }
    }
    float ri = rs_in[node];
    acc.x *= ri; acc.y *= ri; acc.z *= ri; acc.w *= ri;

    float4 o = bs4[l];
    int gbase = g << 4;
    #pragma unroll
    for (int m = 0; m < 16; m++) {
        float ax = __shfl(acc.x, gbase + m, 64);
        float ay = __shfl(acc.y, gbase + m, 64);
        float az = __shfl(acc.z, gbase + m, 64);
        float aw = __shfl(acc.w, gbase + m, 64);
        float4 w0 = Ws4[(4 * m + 0) * 16 + l];
        float4 w1 = Ws4[(4 * m + 1) * 16 + l];
        float4 w2 = Ws4[(4 * m + 2) * 16 + l];
        float4 w3 = Ws4[(4 * m + 3) * 16 + l];
        o.x += ax * w0.x + ay * w1.x + az * w2.x + aw * w3.x;
        o.y += ax * w0.y + ay * w1.y + az * w2.y + aw * w3.y;
        o.z += ax * w0.z + ay * w1.z + az * w2.z + aw * w3.z;
        o.w += ax * w0.w + ay * w1.w + az * w2.w + aw * w3.w;
    }
    if (SCALE_OUT) {
        float ro = rs_out[node];
        o.x = (o.x < 0.f ? 0.f : o.x) * ro;
        o.y = (o.y < 0.f ? 0.f : o.y) * ro;
        o.z = (o.z < 0.f ? 0.f : o.z) * ro;
        o.w = (o.w < 0.f ? 0.f : o.w) * ro;
        h4 ho;
        ho.a = __float22half2_rn(make_float2(o.x, o.y));
        ho.b = __float22half2_rn(make_float2(o.z, o.w));
        ((h4*)outp)[node * 16 + l] = ho;
    } else {
        ((float4*)outp)[node * 16 + l] = o;
    }
}

// ====================== cooperative mega-kernel ======================

struct MegaParams {
    const unsigned* partial;
    float* rs_out;
    const float* rs_in;
    const float4* x4;
    h4* bufA;
    h4* bufB;
    const int* cnt;
    const unsigned char* key;
    int* perm;
    const int* row_start;
    const unsigned short* csr;
    const float* W1; const float* b1;
    const float* W2; const float* b2;
    const float* W3; const float* b3;
    float4* out;
};

__global__ void __launch_bounds__(256, 4) mega(MegaParams p) {
    cg::grid_group grid = cg::this_grid();
    __shared__ float4 Ws4[DIM * 16];      // 16 KB: ONE layer at a time
    __shared__ float4 bs4[3][16];
    __shared__ float rsl[64];
    __shared__ int tots[16], basel[16], binb[16], cur16[16];

    int t = threadIdx.x;
    int j = blockIdx.x;

    if (t < 16) {
        bs4[0][t] = ((const float4*)p.b1)[t];
        bs4[1][t] = ((const float4*)p.b2)[t];
        bs4[2][t] = ((const float4*)p.b3)[t];
    }

    // phase 0a: degree-sort permutation (blocks 0..255, one 256-node slice each)
    if (j < 256) perm_slice(p.cnt, p.key, p.perm, j, t, tots, basel, binb, cur16);
    __syncthreads();

    // phase 0b: rs_out reduce + fp16 prescale (each block: 64 rows)
    if (t < 16) {
        int w = j * 16 + t;                            // word = 4 nodes
        int c0 = 0, c1 = 0, c2 = 0, c3 = 0;
        for (int c = 0; c < HB; c++) {
            unsigned v = p.partial[(size_t)c * OH_WORDS + w];
            c0 += (int)(v & 255u);
            c1 += (int)((v >> 8) & 255u);
            c2 += (int)((v >> 16) & 255u);
            c3 += (int)(v >> 24);
        }
        float4 r = make_float4(rsqrtf(c0 < 1 ? 1.0f : (float)c0),
                               rsqrtf(c1 < 1 ? 1.0f : (float)c1),
                               rsqrtf(c2 < 1 ? 1.0f : (float)c2),
                               rsqrtf(c3 < 1 ? 1.0f : (float)c3));
        ((float4*)p.rs_out)[w] = r;
        rsl[t * 4 + 0] = r.x; rsl[t * 4 + 1] = r.y;
        rsl[t * 4 + 2] = r.z; rsl[t * 4 + 3] = r.w;
    }
    __syncthreads();
    {
        int rowbase = j * 1024;                        // 4-elt units (64 rows)
        for (int i = t; i < 1024; i += 256) {
            float r = rsl[i >> 4];
            float4 v = p.x4[rowbase + i];
            h4 o;
            o.a = __float22half2_rn(make_float2(v.x * r, v.y * r));
            o.b = __float22half2_rn(make_float2(v.z * r, v.w * r));
            p.bufA[rowbase + i] = o;
        }
    }

    grid.sync();

    int wave_id = t >> 6;
    int lane = t & 63;
    int g = lane >> 4;
    int l = lane & 15;

    for (int lay = 0; lay < 3; lay++) {
        {   // stage this layer's W (prior grid.sync doubles as block barrier)
            const float4* Wg = (const float4*)(lay == 0 ? p.W1 : (lay == 1 ? p.W2 : p.W3));
            for (int i = t; i < DIM * 16; i += 256) Ws4[i] = Wg[i];
        }
        __syncthreads();
        const h4* xs = (lay == 1) ? p.bufB : p.bufA;
        void* outp   = (lay == 0) ? (void*)p.bufB : (lay == 1) ? (void*)p.bufA : (void*)p.out;
        for (int tile = j; tile < N_NODES / 16; tile += MB) {
            int node = p.perm[tile * 16 + wave_id * 4 + g];
            if (lay < 2)
                layer_tile<true >(xs, p.row_start, p.csr, p.rs_out, p.rs_in,
                                  Ws4, bs4[lay], outp, node, g, l);
            else
                layer_tile<false>(xs, p.row_start, p.csr, p.rs_out, p.rs_in,
                                  Ws4, bs4[lay], outp, node, g, l);
        }
        if (lay < 2) grid.sync();
    }
}

// ====================== fallback (non-cooperative) ======================

__global__ void perm_build(const int* __restrict__ cnt, const unsigned char* __restrict__ key,
                           int* __restrict__ perm) {
    __shared__ int tots[16], basel[16], binb[16], cur16[16];
    perm_slice(cnt, key, perm, blockIdx.x, threadIdx.x, tots, basel, binb, cur16);
}

__global__ void oh2p_prescale(const unsigned* __restrict__ partial,
                              float* __restrict__ rs_out,
                              const float4* __restrict__ x4, h4* __restrict__ xs) {
    __shared__ float rsl[256];
    int b = blockIdx.x;
    int t = threadIdx.x;
    if (t < 64) {
        int w = b * 64 + t;
        int c0 = 0, c1 = 0, c2 = 0, c3 = 0;
        for (int c = 0; c < HB; c++) {
            unsigned v = partial[(size_t)c * OH_WORDS + w];
            c0 += (int)(v & 255u);
            c1 += (int)((v >> 8) & 255u);
            c2 += (int)((v >> 16) & 255u);
            c3 += (int)(v >> 24);
        }
        float4 r = make_float4(rsqrtf(c0 < 1 ? 1.0f : (float)c0),
                               rsqrtf(c1 < 1 ? 1.0f : (float)c1),
                               rsqrtf(c2 < 1 ? 1.0f : (float)c2),
                               rsqrtf(c3 < 1 ? 1.0f : (float)c3));
        ((float4*)rs_out)[w] = r;
        rsl[t * 4 + 0] = r.x; rsl[t * 4 + 1] = r.y;
        rsl[t * 4 + 2] = r.z; rsl[t * 4 + 3] = r.w;
    }
    __syncthreads();
    int rowbase = b * 4096;
    for (int i = t; i < 4096; i += 256) {
        float r = rsl[i >> 4];
        float4 v = x4[rowbase + i];
        h4 o;
        o.a = __float22half2_rn(make_float2(v.x * r, v.y * r));
        o.b = __float22half2_rn(make_float2(v.z * r, v.w * r));
        xs[rowbase + i] = o;
    }
}

template<bool SCALE_OUT>
__global__ void fused_layer_p(const h4* __restrict__ xs, const int* __restrict__ perm,
                              const int* __restrict__ row_start,
                              const unsigned short* __restrict__ csr,
                              const float* __restrict__ rs_out, const float* __restrict__ rs_in,
                              const float* __restrict__ W, const float* __restrict__ b,
                              void* __restrict__ outp) {
    __shared__ float4 Ws4[DIM * 16];
    __shared__ float4 bs4[16];
    {
        const float4* Wg = (const float4*)W;
        for (int i = threadIdx.x; i < DIM * 16; i += blockDim.x) Ws4[i] = Wg[i];
        if (threadIdx.x < 16) bs4[threadIdx.x] = ((const float4*)b)[threadIdx.x];
    }
    __syncthreads();
    int wave_id = threadIdx.x >> 6;
    int lane = threadIdx.x & 63;
    int g = lane >> 4;
    int l = lane & 15;
    int node = perm[blockIdx.x * 16 + wave_id * 4 + g];
    layer_tile<SCALE_OUT>(xs, row_start, csr, rs_out, rs_in, Ws4, bs4, outp, node, g, l);
}

extern "C" void kernel_launch(void* const* d_in, const int* in_sizes, int n_in,
                              void* d_out, int out_size, void* d_ws, size_t ws_size,
                              hipStream_t stream) {
    const float* x   = (const float*)d_in[0];
    const int*   ei  = (const int*)d_in[1];
    const int*   src = ei;
    const int*   dst = ei + N_EDGES;
    const float* W1 = (const float*)d_in[3];
    const float* b1 = (const float*)d_in[4];
    const float* W2 = (const float*)d_in[5];
    const float* b2 = (const float*)d_in[6];
    const float* W3 = (const float*)d_in[7];
    const float* b3 = (const float*)d_in[8];
    float* out = (float*)d_out;

    // workspace (~29 MB):
    // rs[2N] | row_start[N+256] | block_h[64K] | so[64K] | cnt[4K] | key[64KB] |
    // perm[N] | csr[E+16] u16 | bufA[(N+1)*128B] | bufB[(N+1)*128B] | partial[8MB]
    // alias: bpack (4MB) over bufB head (dead before layer-1 writes bufB).
    char* ws = (char*)d_ws;
    float* rs        = (float*)ws;                                 // [2N]
    float* rs_out    = rs;
    float* rs_in     = rs + N_NODES;
    int*   row_start = (int*)(rs + 2 * N_NODES);                   // [N+256]
    int*   block_h   = row_start + (N_NODES + 256);                // [65536]
    int*   so        = block_h + 256 * CHUNKS;                     // [65536]
    int*   cnt       = so + 256 * CHUNKS;                          // [4096]
    unsigned char* key = (unsigned char*)(cnt + 4096);             // [65536]
    int*   perm      = (int*)(key + N_NODES);                      // [65536]
    unsigned short* csr_src = (unsigned short*)(perm + N_NODES);   // [E+16]
    h4*    bufA      = (h4*)(csr_src + N_EDGES + 16);              // [(N+1)*16]
    h4*    bufB      = bufA + (size_t)(N_NODES + 1) * 16;          // [(N+1)*16]
    unsigned* partial = (unsigned*)(bufB + (size_t)(N_NODES + 1) * 16); // 8 MB
    int*   bpack     = (int*)bufB;                                 // 4 MB alias
    uint2* zeroA     = (uint2*)(bufA + (size_t)N_NODES * 16);      // row N_NODES
    uint2* zeroB     = (uint2*)(bufB + (size_t)N_NODES * 16);

    edge_hist   <<<HB, 256, 0, stream>>>(src, dst, block_h, partial, zeroA, zeroB);
    part_scan   <<<1, 1024, 0, stream>>>(block_h, so);
    part_scatter<<<CHUNKS, 256, 0, stream>>>(src, dst, so, bpack);
    bucket_fused<<<256, 256, 0, stream>>>(bpack, so, row_start, rs_in, csr_src, key, cnt);

    MegaParams p;
    p.partial = partial; p.rs_out = rs_out; p.rs_in = rs_in;
    p.x4 = (const float4*)x; p.bufA = bufA; p.bufB = bufB;
    p.cnt = cnt; p.key = key; p.perm = perm;
    p.row_start = row_start; p.csr = csr_src;
    p.W1 = W1; p.b1 = b1; p.W2 = W2; p.b2 = b2; p.W3 = W3; p.b3 = b3;
    p.out = (float4*)out;
    void* args[] = { &p };
    hipError_t err = hipLaunchCooperativeKernel((void*)mega, dim3(MB), dim3(256),
                                                args, 0, stream);
    if (err != hipSuccess) {
        // fallback: identical math, separate dispatches
        const int fb = N_NODES / 16;
        perm_build   <<<256, 256, 0, stream>>>(cnt, key, perm);
        oh2p_prescale<<<256, 256, 0, stream>>>(partial, rs_out, (const float4*)x, bufA);
        fused_layer_p<true ><<<fb, 256, 0, stream>>>(bufA, perm, row_start, csr_src, rs_out, rs_in, W1, b1, (void*)bufB);
        fused_layer_p<true ><<<fb, 256, 0, stream>>>(bufB, perm, row_start, csr_src, rs_out, rs_in, W2, b2, (void*)bufA);
        fused_layer_p<false><<<fb, 256, 0, stream>>>(bufA, perm, row_start, csr_src, rs_out, rs_in, W3, b3, (void*)out);
    }
}

// Round 12
// 267.984 us; speedup vs baseline: 2.4696x; 2.4696x over previous
//
#include <hip/hip_runtime.h>
#include <hip/hip_fp16.h>

// GraphEncoder: 3x GraphConv(norm='both'), DIM=64, fixed graph.
// R12: revert to R9 launch shape (separate 4096-block layer kernels; mega-kernel
// was 3.5x slower at 4 blocks/CU). Add LPT degree-sorted wave packing: perm[]
// groups nodes of equal ceil(deg/16) so each wave's 4 nodes have equal gather
// trip counts (~24% fewer iterations vs consecutive-node packing).
// fp16 inter-layer tables, fp32 math throughout.

#define N_NODES 65536
#define N_EDGES 1048576
#define DIM 64

#define CHUNKS 256
#define EPC (N_EDGES / CHUNKS)        // 4096 edges per scatter chunk
#define HB 128                        // edge_hist blocks (2 chunks each)
#define OH_WORDS 16384                // 65536 nodes packed 4-per-word (64KB)

struct alignas(8) h4 { __half2 a, b; };   // 4 halves = 8 B

// --- one pass over edges: dst partition hist + packed src hist + zero rows ---
__global__ void edge_hist(const int* __restrict__ src, const int* __restrict__ dst,
                          int* __restrict__ block_hist, unsigned* __restrict__ partial,
                          uint2* __restrict__ zeroA, uint2* __restrict__ zeroB) {
    __shared__ unsigned h[OH_WORDS];  // 64 KB: src histogram, 8-bit x4 packed
    __shared__ int bh[2][256];
    int t = threadIdx.x;
    int j = blockIdx.x;               // 0..127
    for (int i = t; i < OH_WORDS; i += 256) h[i] = 0;
    bh[0][t] = 0; bh[1][t] = 0;
    __syncthreads();
    if (j == 0) {                     // zero row (row N_NODES, 128 B each table)
        if (t < 16) zeroA[t] = make_uint2(0u, 0u);
        else if (t < 32) zeroB[t - 16] = make_uint2(0u, 0u);
    }
    int base = j * (2 * EPC);
    for (int i = t; i < 2 * EPC; i += 256) {
        int s = src[base + i];
        int d = dst[base + i];
        atomicAdd(&h[s >> 2], 1u << ((s & 3) * 8));
        atomicAdd(&bh[i >> 12][d >> 8], 1);
    }
    __syncthreads();
    unsigned* dp = partial + (size_t)j * OH_WORDS;
    for (int i = t; i < OH_WORDS; i += 256) dp[i] = h[i];
    block_hist[t * CHUNKS + 2 * j]     = bh[0][t];
    block_hist[t * CHUNKS + 2 * j + 1] = bh[1][t];
}

// --- exclusive scan of 65536 (bucket-major [bucket][chunk]) ---
__global__ void part_scan(const int* __restrict__ bh, int* __restrict__ so) {
    __shared__ int s[1024];
    int t = threadIdx.x;
    const int4* b4 = (const int4*)(bh + t * 64);
    int4 v[16];
    int sum = 0;
    #pragma unroll
    for (int i = 0; i < 16; i++) {
        v[i] = b4[i];
        sum += v[i].x + v[i].y + v[i].z + v[i].w;
    }
    s[t] = sum;
    __syncthreads();
    for (int off = 1; off < 1024; off <<= 1) {
        int u = (t >= off) ? s[t - off] : 0;
        __syncthreads();
        s[t] += u;
        __syncthreads();
    }
    int run = s[t] - sum;
    int* o = so + t * 64;
    #pragma unroll
    for (int i = 0; i < 16; i++) {
        o[4 * i + 0] = run; run += v[i].x;
        o[4 * i + 1] = run; run += v[i].y;
        o[4 * i + 2] = run; run += v[i].z;
        o[4 * i + 3] = run; run += v[i].w;
    }
}

// --- scatter packed (src | dlow<<16) into bucket order, 256 chunks ---
__global__ void part_scatter(const int* __restrict__ src, const int* __restrict__ dst,
                             const int* __restrict__ so, int* __restrict__ bpack) {
    __shared__ int cur[256];
    cur[threadIdx.x] = so[threadIdx.x * CHUNKS + blockIdx.x];
    __syncthreads();
    int base = blockIdx.x * EPC;
    for (int i = threadIdx.x; i < EPC; i += 256) {
        int s = src[base + i];
        int d = dst[base + i];
        int pos = atomicAdd(&cur[d >> 8], 1);
        bpack[pos] = s | ((d & 255) << 16);
    }
}

// --- per-bucket: hist -> scan -> row_start+rs_in+class key/counts -> csr emit ---
__global__ void bucket_fused(const int* __restrict__ bpack, const int* __restrict__ so,
                             int* __restrict__ row_start, float* __restrict__ rs_in,
                             unsigned short* __restrict__ csr_src,
                             unsigned char* __restrict__ key, int* __restrict__ cnt) {
    __shared__ int stage[8192];                        // 32 KB
    __shared__ int h[256], sc[256], cur[256];
    __shared__ int cnt16[16];
    int b = blockIdx.x;
    int t = threadIdx.x;
    int beg = so[b * CHUNKS];
    int end = (b == 255) ? N_EDGES : so[(b + 1) * CHUNKS];
    int n = end - beg;
    h[t] = 0;
    if (t < 16) cnt16[t] = 0;
    __syncthreads();
    for (int i = t; i < n; i += 256) {
        int p = bpack[beg + i];
        if (i < 8192) stage[i] = p;
        atomicAdd(&h[(p >> 16) & 255], 1);
    }
    __syncthreads();
    int d = h[t];
    sc[t] = d;
    __syncthreads();
    for (int off = 1; off < 256; off <<= 1) {
        int v = (t >= off) ? sc[t - off] : 0;
        __syncthreads();
        sc[t] += v;
        __syncthreads();
    }
    int rsv = beg + sc[t] - d;
    int node = b * 256 + t;
    row_start[node] = rsv;
    rs_in[node] = rsqrtf(d < 1 ? 1.0f : (float)d);
    if (node == N_NODES - 1) row_start[N_NODES] = N_EDGES;
    // degree class (descending trip count = LPT): k = 15 - min(15, ceil(d/16))
    int c = (d + 15) >> 4; if (c > 15) c = 15;
    int k = 15 - c;
    key[node] = (unsigned char)k;
    atomicAdd(&cnt16[k], 1);
    cur[t] = rsv;
    __syncthreads();
    if (t < 16) cnt[b * 16 + t] = cnt16[t];
    for (int i = t; i < n; i += 256) {
        int p = (i < 8192) ? stage[i] : bpack[beg + i];
        int pos = atomicAdd(&cur[(p >> 16) & 255], 1);
        csr_src[pos] = (unsigned short)(p & 0xFFFF);
    }
}

// --- LPT permutation: 16-bin counting sort of nodes by degree class ---
__global__ void perm_build(const int* __restrict__ cnt, const unsigned char* __restrict__ key,
                           int* __restrict__ perm) {
    __shared__ int tots[16], basel[16], binb[16], cur16[16];
    int j = blockIdx.x;
    int t = threadIdx.x;
    if (t < 16) {
        int run = 0, bj = 0;
        for (int j2 = 0; j2 < 256; j2++) {
            if (j2 == j) bj = run;
            run += cnt[j2 * 16 + t];
        }
        tots[t] = run;
        basel[t] = bj;
    }
    __syncthreads();
    if (t == 0) {
        int r = 0;
        for (int i = 0; i < 16; i++) { binb[i] = r; r += tots[i]; }
    }
    __syncthreads();
    if (t < 16) cur16[t] = binb[t] + basel[t];
    __syncthreads();
    int node = j * 256 + t;
    int k = key[node];
    int pos = atomicAdd(&cur16[k], 1);
    perm[pos] = node;
}

// --- reduce src histograms -> rs_out, fused with fp16 prescale xs = x*rs_out ---
__global__ void oh2p_prescale(const unsigned* __restrict__ partial,
                              float* __restrict__ rs_out,
                              const float4* __restrict__ x4, h4* __restrict__ xs) {
    __shared__ float rsl[256];
    int b = blockIdx.x;
    int t = threadIdx.x;
    if (t < 64) {
        int w = b * 64 + t;
        int c0 = 0, c1 = 0, c2 = 0, c3 = 0;
        for (int c = 0; c < HB; c++) {
            unsigned v = partial[(size_t)c * OH_WORDS + w];
            c0 += (int)(v & 255u);
            c1 += (int)((v >> 8) & 255u);
            c2 += (int)((v >> 16) & 255u);
            c3 += (int)(v >> 24);
        }
        float4 r = make_float4(rsqrtf(c0 < 1 ? 1.0f : (float)c0),
                               rsqrtf(c1 < 1 ? 1.0f : (float)c1),
                               rsqrtf(c2 < 1 ? 1.0f : (float)c2),
                               rsqrtf(c3 < 1 ? 1.0f : (float)c3));
        ((float4*)rs_out)[w] = r;
        rsl[t * 4 + 0] = r.x; rsl[t * 4 + 1] = r.y;
        rsl[t * 4 + 2] = r.z; rsl[t * 4 + 3] = r.w;
    }
    __syncthreads();
    int rowbase = b * 4096;
    for (int i = t; i < 4096; i += 256) {
        float r = rsl[i >> 4];
        float4 v = x4[rowbase + i];
        h4 o;
        o.a = __float22half2_rn(make_float2(v.x * r, v.y * r));
        o.b = __float22half2_rn(make_float2(v.z * r, v.w * r));
        xs[rowbase + i] = o;
    }
}

// --- fused layer (perm-indexed): 4 equal-class nodes/wave, 16 lanes/node ---
template<bool SCALE_OUT>
__global__ void fused_layer_p(const h4* __restrict__ xs, const int* __restrict__ perm,
                              const int* __restrict__ row_start,
                              const unsigned short* __restrict__ csr,
                              const float* __restrict__ rs_out, const float* __restrict__ rs_in,
                              const float* __restrict__ W, const float* __restrict__ b,
                              void* __restrict__ outp) {
    __shared__ float4 Ws4[DIM * 16];
    __shared__ float4 bs4[16];
    {
        const float4* Wg = (const float4*)W;
        for (int i = threadIdx.x; i < DIM * 16; i += blockDim.x) Ws4[i] = Wg[i];
        if (threadIdx.x < 16) bs4[threadIdx.x] = ((const float4*)b)[threadIdx.x];
    }
    __syncthreads();

    int wave_id = threadIdx.x >> 6;
    int lane = threadIdx.x & 63;
    int g = lane >> 4;
    int l = lane & 15;
    int node = perm[blockIdx.x * 16 + wave_id * 4 + g];

    int beg = row_start[node];
    int end = row_start[node + 1];

    float4 acc = make_float4(0.f, 0.f, 0.f, 0.f);
    for (int k = beg; k < end; k += 16) {
        int s[16];
        #pragma unroll
        for (int jj = 0; jj < 16; jj++) {
            int kk = k + jj;
            int idx = csr[kk];                         // csr padded by 16 -> safe
            s[jj] = (kk < end) ? idx : N_NODES;        // OOB -> zero row (L1-hot)
        }
        h4 v[16];
        #pragma unroll
        for (int jj = 0; jj < 16; jj++) v[jj] = xs[s[jj] * 16 + l];
        #pragma unroll
        for (int jj = 0; jj < 16; jj++) {
            float2 lo = __half22float2(v[jj].a);
            float2 hi = __half22float2(v[jj].b);
            acc.x += lo.x; acc.y += lo.y; acc.z += hi.x; acc.w += hi.y;
        }
    }
    float ri = rs_in[node];
    acc.x *= ri; acc.y *= ri; acc.z *= ri; acc.w *= ri;

    float4 o = bs4[l];
    int gbase = g << 4;
    #pragma unroll
    for (int m = 0; m < 16; m++) {
        float ax = __shfl(acc.x, gbase + m, 64);
        float ay = __shfl(acc.y, gbase + m, 64);
        float az = __shfl(acc.z, gbase + m, 64);
        float aw = __shfl(acc.w, gbase + m, 64);
        float4 w0 = Ws4[(4 * m + 0) * 16 + l];
        float4 w1 = Ws4[(4 * m + 1) * 16 + l];
        float4 w2 = Ws4[(4 * m + 2) * 16 + l];
        float4 w3 = Ws4[(4 * m + 3) * 16 + l];
        o.x += ax * w0.x + ay * w1.x + az * w2.x + aw * w3.x;
        o.y += ax * w0.y + ay * w1.y + az * w2.y + aw * w3.y;
        o.z += ax * w0.z + ay * w1.z + az * w2.z + aw * w3.z;
        o.w += ax * w0.w + ay * w1.w + az * w2.w + aw * w3.w;
    }
    if (SCALE_OUT) {
        float ro = rs_out[node];
        o.x = (o.x < 0.f ? 0.f : o.x) * ro;
        o.y = (o.y < 0.f ? 0.f : o.y) * ro;
        o.z = (o.z < 0.f ? 0.f : o.z) * ro;
        o.w = (o.w < 0.f ? 0.f : o.w) * ro;
        h4 ho;
        ho.a = __float22half2_rn(make_float2(o.x, o.y));
        ho.b = __float22half2_rn(make_float2(o.z, o.w));
        ((h4*)outp)[node * 16 + l] = ho;
    } else {
        ((float4*)outp)[node * 16 + l] = o;
    }
}

extern "C" void kernel_launch(void* const* d_in, const int* in_sizes, int n_in,
                              void* d_out, int out_size, void* d_ws, size_t ws_size,
                              hipStream_t stream) {
    const float* x   = (const float*)d_in[0];
    const int*   ei  = (const int*)d_in[1];
    const int*   src = ei;
    const int*   dst = ei + N_EDGES;
    const float* W1 = (const float*)d_in[3];
    const float* b1 = (const float*)d_in[4];
    const float* W2 = (const float*)d_in[5];
    const float* b2 = (const float*)d_in[6];
    const float* W3 = (const float*)d_in[7];
    const float* b3 = (const float*)d_in[8];
    float* out = (float*)d_out;

    // workspace (~29 MB):
    // rs[2N] | row_start[N+256] | block_h[64K] | so[64K] | cnt[4K] | key[64KB] |
    // perm[N] | csr[E+16] u16 | bufA[(N+1)*128B] | bufB[(N+1)*128B] | partial[8MB]
    // alias: bpack (4MB) over bufB head (dead before layer-1 writes bufB).
    char* ws = (char*)d_ws;
    float* rs        = (float*)ws;                                 // [2N]
    float* rs_out    = rs;
    float* rs_in     = rs + N_NODES;
    int*   row_start = (int*)(rs + 2 * N_NODES);                   // [N+256]
    int*   block_h   = row_start + (N_NODES + 256);                // [65536]
    int*   so        = block_h + 256 * CHUNKS;                     // [65536]
    int*   cnt       = so + 256 * CHUNKS;                          // [4096]
    unsigned char* key = (unsigned char*)(cnt + 4096);             // [65536]
    int*   perm      = (int*)(key + N_NODES);                      // [65536]
    unsigned short* csr_src = (unsigned short*)(perm + N_NODES);   // [E+16]
    h4*    bufA      = (h4*)(csr_src + N_EDGES + 16);              // [(N+1)*16]
    h4*    bufB      = bufA + (size_t)(N_NODES + 1) * 16;          // [(N+1)*16]
    unsigned* partial = (unsigned*)(bufB + (size_t)(N_NODES + 1) * 16); // 8 MB
    int*   bpack     = (int*)bufB;                                 // 4 MB alias
    uint2* zeroA     = (uint2*)(bufA + (size_t)N_NODES * 16);      // row N_NODES
    uint2* zeroB     = (uint2*)(bufB + (size_t)N_NODES * 16);

    const int fb = N_NODES / 16;      // 4096 blocks for fused layers

    edge_hist    <<<HB, 256, 0, stream>>>(src, dst, block_h, partial, zeroA, zeroB);
    part_scan    <<<1, 1024, 0, stream>>>(block_h, so);
    part_scatter <<<CHUNKS, 256, 0, stream>>>(src, dst, so, bpack);
    bucket_fused <<<256, 256, 0, stream>>>(bpack, so, row_start, rs_in, csr_src, key, cnt);
    perm_build   <<<256, 256, 0, stream>>>(cnt, key, perm);
    oh2p_prescale<<<256, 256, 0, stream>>>(partial, rs_out, (const float4*)x, bufA);

    // layers: bufA -> bufB(fp16, scaled) -> bufA(fp16, scaled) -> d_out (fp32)
    fused_layer_p<true ><<<fb, 256, 0, stream>>>(bufA, perm, row_start, csr_src, rs_out, rs_in, W1, b1, (void*)bufB);
    fused_layer_p<true ><<<fb, 256, 0, stream>>>(bufB, perm, row_start, csr_src, rs_out, rs_in, W2, b2, (void*)bufA);
    fused_layer_p<false><<<fb, 256, 0, stream>>>(bufA, perm, row_start, csr_src, rs_out, rs_in, W3, b3, (void*)out);
}